// Round 7
// baseline (1082.024 us; speedup 1.0000x reference)
//
#include <hip/hip_runtime.h>

// GConv: out = spmm(A0, S) + spmm(A1, S) + bias,  S = x @ W
// N=100000, E=600000, F_IN=F_OUT=128.
// R7: no global scattered atomics (measured ~20 G/s vs 157 G/s coalesced).
// Build: 2-pass LDS-histogram binning into 64-row buckets (records land in
// contiguous per-(bucket,block) runs -> ~2x write amp, not 8x).
// Pull: block per bucket, 32KB LDS fp32 accumulator (4 blocks/CU), record
// chunks staged to LDS, gathers unrolled 4x, LDS atomics conflict-free.

#define FDIM 128
#define BROWS 64          // rows per bucket
#define EPB 4096          // edges per binning block
#define SCAN_TILE 2048
#define MAXBUCKETS 2048

typedef __attribute__((ext_vector_type(8))) short short8;
typedef __attribute__((ext_vector_type(4))) float floatx4;

__device__ __forceinline__ unsigned short f32_to_bf16(float f) {
    unsigned int u = __float_as_uint(f);
    unsigned int r = u + 0x7fffu + ((u >> 16) & 1u);   // RNE
    return (unsigned short)(r >> 16);
}
__device__ __forceinline__ float bf16u_to_f32(unsigned short u) {
    return __uint_as_float(((unsigned int)u) << 16);
}

// ---------------- Wt[n][k] = bf16(W[k][n]) — one-shot ----------------------
__global__ __launch_bounds__(256) void wt_conv(const float* __restrict__ w,
                                               unsigned short* __restrict__ wt) {
    int idx = blockIdx.x * 256 + threadIdx.x;   // 0..16383
    int nn = idx >> 7, k = idx & 127;
    wt[idx] = f32_to_bf16(w[(size_t)k * FDIM + nn]);
}

// ---------------- GEMM: support(bf16) = x @ W via MFMA ---------------------
__global__ __launch_bounds__(256) void gemm_mfma(const float* __restrict__ x,
                                                 const unsigned short* __restrict__ wt,
                                                 unsigned short* __restrict__ support,
                                                 int n) {
    __shared__ __align__(16) short As[64][136];
    __shared__ __align__(16) short Bs[128][136];
    const int tid = threadIdx.x;
    const int m0 = blockIdx.x * 64;

    #pragma unroll
    for (int i = 0; i < 8; ++i) {
        int idx = tid + i * 256;
        int r = idx >> 5, c4 = idx & 31;
        float4 v = make_float4(0.f, 0.f, 0.f, 0.f);
        if (m0 + r < n) v = *(const float4*)(x + (size_t)(m0 + r) * FDIM + c4 * 4);
        short4 s;
        s.x = (short)f32_to_bf16(v.x); s.y = (short)f32_to_bf16(v.y);
        s.z = (short)f32_to_bf16(v.z); s.w = (short)f32_to_bf16(v.w);
        *(short4*)&As[r][c4 * 4] = s;
    }
    #pragma unroll
    for (int i = 0; i < 8; ++i) {
        int idx = tid + i * 256;
        int r = idx >> 4, c8 = idx & 15;
        short8 v = *(const short8*)(wt + (size_t)r * FDIM + c8 * 8);
        *(short8*)&Bs[r][c8 * 8] = v;
    }
    __syncthreads();

    const int wv = tid >> 6;
    const int lane = tid & 63;
    const int quad = lane >> 4;
    const int lr = lane & 15;

    floatx4 acc[8];
    #pragma unroll
    for (int nt = 0; nt < 8; ++nt) acc[nt] = (floatx4)0.f;

    #pragma unroll
    for (int ks = 0; ks < 4; ++ks) {
        short8 a = *(const short8*)&As[wv * 16 + lr][ks * 32 + quad * 8];
        #pragma unroll
        for (int nt = 0; nt < 8; ++nt) {
            short8 b = *(const short8*)&Bs[nt * 16 + lr][ks * 32 + quad * 8];
            acc[nt] = __builtin_amdgcn_mfma_f32_16x16x32_bf16(a, b, acc[nt], 0, 0, 0);
        }
    }

    #pragma unroll
    for (int i = 0; i < 4; ++i) {
        int row = m0 + wv * 16 + quad * 4 + i;
        if (row < n) {
            #pragma unroll
            for (int nt = 0; nt < 8; ++nt)
                support[(size_t)row * FDIM + nt * 16 + lr] = f32_to_bf16(acc[nt][i]);
        }
    }
}

// ---------------- pass A: per-block bucket histogram (LDS atomics only) ----
__global__ __launch_bounds__(256) void pass_a(const int* __restrict__ rows0,
                                              const int* __restrict__ rows1,
                                              int* __restrict__ counts,   // [bucket][blk]
                                              int E, int nBuckets, int nBlk) {
    __shared__ int hist[MAXBUCKETS];
    const int tid = threadIdx.x;
    const int blk = blockIdx.x;
    for (int b = tid; b < nBuckets; b += 256) hist[b] = 0;
    __syncthreads();
    const int s = blk * EPB;
    const int e = min(s + EPB, 2 * E);
    for (int i = s + tid; i < e; i += 256) {
        int r = (i < E) ? rows0[i] : rows1[i - E];
        atomicAdd(&hist[r / BROWS], 1);
    }
    __syncthreads();
    for (int b = tid; b < nBuckets; b += 256)
        counts[(size_t)b * nBlk + blk] = hist[b];
}

// ---------------- 3-phase device-wide exclusive scan -----------------------
__global__ __launch_bounds__(256) void scan_p1(const int* __restrict__ counts,
                                               int* __restrict__ blockSums, int len) {
    __shared__ int sdata[256];
    const int t = threadIdx.x;
    const int base = blockIdx.x * SCAN_TILE + t * 8;
    int sum = 0;
    #pragma unroll
    for (int i = 0; i < 8; ++i) {
        int idx = base + i;
        if (idx < len) sum += counts[idx];
    }
    sdata[t] = sum;
    __syncthreads();
    for (int d = 128; d > 0; d >>= 1) {
        if (t < d) sdata[t] += sdata[t + d];
        __syncthreads();
    }
    if (t == 0) blockSums[blockIdx.x] = sdata[0];
}

__global__ __launch_bounds__(512) void scan_p2(int* __restrict__ blockSums, int nb) {
    __shared__ int sdata[512];
    const int t = threadIdx.x;
    int v = (t < nb) ? blockSums[t] : 0;
    sdata[t] = v;
    __syncthreads();
    for (int d = 1; d < 512; d <<= 1) {
        int u = (t >= d) ? sdata[t - d] : 0;
        __syncthreads();
        sdata[t] += u;
        __syncthreads();
    }
    if (t < nb) blockSums[t] = sdata[t] - v;
}

__global__ __launch_bounds__(256) void scan_p3(const int* __restrict__ counts,
                                               const int* __restrict__ blockSums,
                                               int* __restrict__ scanned, int len) {
    __shared__ int sdata[256];
    const int t = threadIdx.x;
    const int base = blockIdx.x * SCAN_TILE + t * 8;
    int loc[8];
    int sum = 0;
    #pragma unroll
    for (int i = 0; i < 8; ++i) {
        int idx = base + i;
        int c = (idx < len) ? counts[idx] : 0;
        loc[i] = sum;
        sum += c;
    }
    sdata[t] = sum;
    __syncthreads();
    const int mine = sum;
    for (int d = 1; d < 256; d <<= 1) {
        int u = (t >= d) ? sdata[t - d] : 0;
        __syncthreads();
        sdata[t] += u;
        __syncthreads();
    }
    const int off = sdata[t] - mine + blockSums[blockIdx.x];
    #pragma unroll
    for (int i = 0; i < 8; ++i) {
        int idx = base + i;
        if (idx < len) scanned[idx] = off + loc[i];
    }
}

// ---------------- pass B: bin records into bucket-contiguous runs ----------
__global__ __launch_bounds__(256) void pass_b(const int* __restrict__ rows0,
                                              const int* __restrict__ cols0,
                                              const float* __restrict__ vals0,
                                              const int* __restrict__ rows1,
                                              const int* __restrict__ cols1,
                                              const float* __restrict__ vals1,
                                              const int* __restrict__ scanned,
                                              int2* __restrict__ rec,
                                              int E, int nBuckets, int nBlk) {
    __shared__ int cur[MAXBUCKETS];
    const int tid = threadIdx.x;
    const int blk = blockIdx.x;
    for (int b = tid; b < nBuckets; b += 256)
        cur[b] = scanned[(size_t)b * nBlk + blk];
    __syncthreads();
    const int s = blk * EPB;
    const int e = min(s + EPB, 2 * E);
    for (int i = s + tid; i < e; i += 256) {
        int r, c; float v;
        if (i < E) { r = rows0[i]; c = cols0[i]; v = vals0[i]; }
        else       { int j = i - E; r = rows1[j]; c = cols1[j]; v = vals1[j]; }
        int b = r / BROWS;
        int pos = atomicAdd(&cur[b], 1);
        rec[pos] = make_int2(((r & (BROWS - 1)) << 24) | c, __float_as_int(v));
    }
}

// ---------------- pull: block per bucket, LDS fp32 accumulator -------------
__global__ __launch_bounds__(256) void pull_bucket(const unsigned short* __restrict__ support,
                                                   const int* __restrict__ scanned,
                                                   const int2* __restrict__ rec,
                                                   const float* __restrict__ bias,
                                                   float* __restrict__ out,
                                                   int n, int nBuckets, int nBlk,
                                                   int totalRec) {
    __shared__ float acc[BROWS * FDIM];          // 32 KB
    __shared__ int2 meta[256];
    const int tid = threadIdx.x;
    const int b = blockIdx.x;
    const int row0 = b * BROWS;
    const int s = scanned[(size_t)b * nBlk];
    const int e = (b + 1 < nBuckets) ? scanned[(size_t)(b + 1) * nBlk] : totalRec;

    #pragma unroll
    for (int i = 0; i < (BROWS * FDIM / 4) / 256; ++i)
        *(float4*)&acc[(tid + i * 256) * 4] = make_float4(0.f, 0.f, 0.f, 0.f);
    __syncthreads();

    const int lane = tid & 63;
    const int wv = tid >> 6;

    for (int base = s; base < e; base += 256) {
        int len = min(256, e - base);
        if (tid < len) meta[tid] = rec[base + tid];
        __syncthreads();
        int j = wv;
        for (; j + 12 < len; j += 16) {          // 4 records in flight per wave
            int2 m0 = meta[j], m1 = meta[j + 4], m2 = meta[j + 8], m3 = meta[j + 12];
            int c0 = m0.x & 0xFFFFFF, c1 = m1.x & 0xFFFFFF,
                c2 = m2.x & 0xFFFFFF, c3 = m3.x & 0xFFFFFF;
            unsigned short a0 = support[(size_t)c0 * FDIM + lane];
            unsigned short b0 = support[(size_t)c0 * FDIM + 64 + lane];
            unsigned short a1 = support[(size_t)c1 * FDIM + lane];
            unsigned short b1 = support[(size_t)c1 * FDIM + 64 + lane];
            unsigned short a2 = support[(size_t)c2 * FDIM + lane];
            unsigned short b2 = support[(size_t)c2 * FDIM + 64 + lane];
            unsigned short a3 = support[(size_t)c3 * FDIM + lane];
            unsigned short b3 = support[(size_t)c3 * FDIM + 64 + lane];
            int r0 = ((unsigned)m0.x) >> 24, r1 = ((unsigned)m1.x) >> 24;
            int r2 = ((unsigned)m2.x) >> 24, r3 = ((unsigned)m3.x) >> 24;
            float v0 = __int_as_float(m0.y), v1 = __int_as_float(m1.y);
            float v2 = __int_as_float(m2.y), v3 = __int_as_float(m3.y);
            atomicAdd(&acc[r0 * FDIM + lane],      v0 * bf16u_to_f32(a0));
            atomicAdd(&acc[r0 * FDIM + 64 + lane], v0 * bf16u_to_f32(b0));
            atomicAdd(&acc[r1 * FDIM + lane],      v1 * bf16u_to_f32(a1));
            atomicAdd(&acc[r1 * FDIM + 64 + lane], v1 * bf16u_to_f32(b1));
            atomicAdd(&acc[r2 * FDIM + lane],      v2 * bf16u_to_f32(a2));
            atomicAdd(&acc[r2 * FDIM + 64 + lane], v2 * bf16u_to_f32(b2));
            atomicAdd(&acc[r3 * FDIM + lane],      v3 * bf16u_to_f32(a3));
            atomicAdd(&acc[r3 * FDIM + 64 + lane], v3 * bf16u_to_f32(b3));
        }
        for (; j < len; j += 4) {
            int2 m = meta[j];
            int c = m.x & 0xFFFFFF;
            int rl = ((unsigned)m.x) >> 24;
            float v = __int_as_float(m.y);
            unsigned short a = support[(size_t)c * FDIM + lane];
            unsigned short bq = support[(size_t)c * FDIM + 64 + lane];
            atomicAdd(&acc[rl * FDIM + lane],      v * bf16u_to_f32(a));
            atomicAdd(&acc[rl * FDIM + 64 + lane], v * bf16u_to_f32(bq));
        }
        __syncthreads();
    }

    // epilogue: out[row] = acc[row] + bias (coalesced float4)
    const int f4 = tid & 31;
    float4 bb = *(const float4*)(bias + f4 * 4);
    #pragma unroll
    for (int k = 0; k < (BROWS * FDIM / 4) / 256; ++k) {
        int idx = tid + k * 256;
        int r = idx >> 5;
        if (row0 + r < n) {
            float4 a = *(float4*)&acc[r * FDIM + f4 * 4];
            a.x += bb.x; a.y += bb.y; a.z += bb.z; a.w += bb.w;
            *(float4*)(out + (size_t)(row0 + r) * FDIM + f4 * 4) = a;
        }
    }
}

// ---------------- fallback: atomic scatter ---------------------------------
__global__ __launch_bounds__(256) void init_bias(const float* __restrict__ bias,
                                                 float* __restrict__ out, int n) {
    int idx = blockIdx.x * 256 + threadIdx.x;
    int total = n * (FDIM / 4);
    if (idx < total) {
        int j = (idx & (FDIM / 4 - 1)) * 4;
        float4 b = *(const float4*)(bias + j);
        *(float4*)(out + (size_t)idx * 4) = b;
    }
}

__global__ __launch_bounds__(256) void scatter_bf16(
    const unsigned short* __restrict__ support,
    const int* __restrict__ rows0, const int* __restrict__ cols0, const float* __restrict__ vals0,
    const int* __restrict__ rows1, const int* __restrict__ cols1, const float* __restrict__ vals1,
    float* __restrict__ out, int E) {
    int gid = blockIdx.x * 256 + threadIdx.x;
    int lane = gid & 63;
    int eg = gid >> 6;
    if (eg >= 2 * E) return;
    int r, c; float v;
    if (eg < E) { r = rows0[eg]; c = cols0[eg]; v = vals0[eg]; }
    else        { int e = eg - E; r = rows1[e]; c = cols1[e]; v = vals1[e]; }
    unsigned short a = support[(size_t)c * FDIM + lane * 2];
    unsigned short bq = support[(size_t)c * FDIM + lane * 2 + 1];
    float* op = out + (size_t)r * FDIM + lane * 2;
    atomicAdd(op,     bf16u_to_f32(a) * v);
    atomicAdd(op + 1, bf16u_to_f32(bq) * v);
}

static inline size_t align256(size_t v) { return (v + 255) & ~(size_t)255; }

extern "C" void kernel_launch(void* const* d_in, const int* in_sizes, int n_in,
                              void* d_out, int out_size, void* d_ws, size_t ws_size,
                              hipStream_t stream) {
    const float* x     = (const float*)d_in[0];
    const float* w     = (const float*)d_in[1];
    const float* bias  = (const float*)d_in[2];
    const float* vals0 = (const float*)d_in[3];
    const float* vals1 = (const float*)d_in[4];
    const int*   rows0 = (const int*)d_in[5];
    const int*   cols0 = (const int*)d_in[6];
    const int*   rows1 = (const int*)d_in[7];
    const int*   cols1 = (const int*)d_in[8];
    const int n = in_sizes[0] / FDIM;
    const int E = in_sizes[3];
    float* out = (float*)d_out;

    const int nBuckets = (n + BROWS - 1) / BROWS;              // 1563
    const int nBlk = (2 * E + EPB - 1) / EPB;                  // 293
    const int scanLen = nBuckets * nBlk;                       // ~458k
    const int nScanBlocks = (scanLen + SCAN_TILE - 1) / SCAN_TILE;  // 224

    size_t off = 0;
    unsigned short* support = (unsigned short*)((char*)d_ws + off);
    off = align256(off + (size_t)n * FDIM * 2);
    unsigned short* wt = (unsigned short*)((char*)d_ws + off);
    off = align256(off + (size_t)FDIM * FDIM * 2);
    int*  counts    = (int*)((char*)d_ws + off);  off = align256(off + (size_t)scanLen * 4);
    int*  scanned   = (int*)((char*)d_ws + off);  off = align256(off + (size_t)scanLen * 4);
    int*  blockSums = (int*)((char*)d_ws + off);  off = align256(off + (size_t)nScanBlocks * 4);
    int2* rec       = (int2*)((char*)d_ws + off); off = align256(off + (size_t)2 * E * 8);

    wt_conv<<<(FDIM * FDIM) / 256, 256, 0, stream>>>(w, wt);
    gemm_mfma<<<(n + 63) / 64, 256, 0, stream>>>(x, wt, support, n);

    if (off <= ws_size && nBuckets <= MAXBUCKETS && nScanBlocks <= 512) {
        pass_a<<<nBlk, 256, 0, stream>>>(rows0, rows1, counts, E, nBuckets, nBlk);
        scan_p1<<<nScanBlocks, 256, 0, stream>>>(counts, blockSums, scanLen);
        scan_p2<<<1, 512, 0, stream>>>(blockSums, nScanBlocks);
        scan_p3<<<nScanBlocks, 256, 0, stream>>>(counts, blockSums, scanned, scanLen);
        pass_b<<<nBlk, 256, 0, stream>>>(rows0, cols0, vals0, rows1, cols1, vals1,
                                         scanned, rec, E, nBuckets, nBlk);
        pull_bucket<<<nBuckets, 256, 0, stream>>>(support, scanned, rec, bias, out,
                                                  n, nBuckets, nBlk, 2 * E);
    } else {
        int total4 = n * (FDIM / 4);
        init_bias<<<(total4 + 255) / 256, 256, 0, stream>>>(bias, out, n);
        long long tthreads = 2LL * E * 64;
        int blocks = (int)((tthreads + 255) / 256);
        scatter_bf16<<<blocks, 256, 0, stream>>>(support, rows0, cols0, vals0,
                                                 rows1, cols1, vals1, out, E);
    }
}